// Round 1
// baseline (326.724 us; speedup 1.0000x reference)
//
#include <hip/hip_runtime.h>

// Problem constants
constexpr int CXR = 15, ECG = 14, EHR = 13;
constexpr int TOTAL = 42;          // CXR+ECG+EHR
constexpr int MPITCH = 44;         // padded row pitch (multiple of 4 for float4)
constexpr float LN_EPS = 1e-5f;

// Workspace layout (floats)
constexpr int WS_M    = 0;         // fused matrix, 42 rows x 44 pitch
constexpr int WS_B    = TOTAL * MPITCH;      // 1848: fused bias (42)
constexpr int WS_G    = WS_B + TOTAL;        // 1890: ln gamma (42)
constexpr int WS_BETA = WS_G + TOTAL;        // 1932: ln beta  (42)
constexpr int WS_FLOATS = WS_BETA + TOTAL;   // 1974

// Main-kernel tiling
constexpr int ROWS = 256;                    // rows per block
constexpr int S_CXR = 0;
constexpr int S_ECG = ROWS * CXR;            // 3840
constexpr int S_EHR = S_ECG + ROWS * ECG;    // 7424
constexpr int STAGE_FLOATS = S_EHR + ROWS * EHR;  // 10752

struct FuseArgs {
    const float *in_w, *in_b, *out_w, *out_b, *kv_w, *kv_b, *ln_g, *ln_b;
    int E, R;
};

// One block per branch: builds fused A_eff = out_w @ Wv @ kv_w (E x 42),
// b_eff = out_w @ (Wv @ kv_b + bv) + out_b, and copies ln gamma/beta.
__global__ void fuse_weights_kernel(FuseArgs a0, FuseArgs a1, FuseArgs a2,
                                    float* __restrict__ ws) {
    FuseArgs a = (blockIdx.x == 0) ? a0 : (blockIdx.x == 1 ? a1 : a2);
    const int E = a.E, R = a.R;
    const int tid = threadIdx.x;

    __shared__ float T1[15 * 42];   // Wv @ kv_w
    __shared__ float b1[15];        // Wv @ kv_b + bv

    // T1[i][j] = sum_k in_w[(2E+i)*E + k] * kv_w[k*42 + j]
    for (int idx = tid; idx < E * TOTAL; idx += blockDim.x) {
        int i = idx / TOTAL, j = idx % TOTAL;
        float acc = 0.f;
        for (int k = 0; k < E; ++k)
            acc = fmaf(a.in_w[(2 * E + i) * E + k], a.kv_w[k * TOTAL + j], acc);
        T1[i * TOTAL + j] = acc;
    }
    if (tid < E) {
        float acc = a.in_b[2 * E + tid];
        for (int k = 0; k < E; ++k)
            acc = fmaf(a.in_w[(2 * E + tid) * E + k], a.kv_b[k], acc);
        b1[tid] = acc;
    }
    __syncthreads();

    // ws M rows [R, R+E): A[i][j] = sum_k out_w[i*E+k] * T1[k*42+j]; pad cols 42,43 = 0
    for (int idx = tid; idx < E * MPITCH; idx += blockDim.x) {
        int i = idx / MPITCH, j = idx % MPITCH;
        float acc = 0.f;
        if (j < TOTAL)
            for (int k = 0; k < E; ++k)
                acc = fmaf(a.out_w[i * E + k], T1[k * TOTAL + j], acc);
        ws[WS_M + (R + i) * MPITCH + j] = acc;
    }
    if (tid < E) {
        float acc = a.out_b[tid];
        for (int k = 0; k < E; ++k)
            acc = fmaf(a.out_w[tid * E + k], b1[k], acc);
        ws[WS_B + R + tid]    = acc;
        ws[WS_G + R + tid]    = a.ln_g[tid];
        ws[WS_BETA + R + tid] = a.ln_b[tid];
    }
}

template <int E, int R, int SBASE>
__device__ __forceinline__ void seg_compute(const float (&ctx)[MPITCH],
                                            const float* __restrict__ wsm,
                                            float* __restrict__ stage,
                                            int tid) {
    float y[E];
#pragma unroll
    for (int i = 0; i < E; ++i) {
        float acc = wsm[WS_B + R + i];
        const float4* wrow = (const float4*)(wsm + WS_M + (R + i) * MPITCH);
#pragma unroll
        for (int q = 0; q < MPITCH / 4; ++q) {
            float4 w = wrow[q];
            acc = fmaf(w.x, ctx[4 * q + 0], acc);
            acc = fmaf(w.y, ctx[4 * q + 1], acc);
            acc = fmaf(w.z, ctx[4 * q + 2], acc);
            acc = fmaf(w.w, ctx[4 * q + 3], acc);
        }
        y[i] = ctx[R + i] + acc;   // residual
    }
    float mu = 0.f;
#pragma unroll
    for (int i = 0; i < E; ++i) mu += y[i];
    mu *= (1.0f / E);
    float var = 0.f;
#pragma unroll
    for (int i = 0; i < E; ++i) { float d = y[i] - mu; var = fmaf(d, d, var); }
    var *= (1.0f / E);
    float rs = rsqrtf(var + LN_EPS);
#pragma unroll
    for (int i = 0; i < E; ++i) {
        float n = (y[i] - mu) * rs;
        stage[SBASE + tid * E + i] = fmaf(n, wsm[WS_G + R + i], wsm[WS_BETA + R + i]);
    }
}

__global__ __launch_bounds__(256) void cmca_main(const float* __restrict__ cxr,
                                                 const float* __restrict__ ecg,
                                                 const float* __restrict__ ehr,
                                                 const float* __restrict__ ws,
                                                 float* __restrict__ out_cxr,
                                                 float* __restrict__ out_ecg,
                                                 float* __restrict__ out_ehr) {
    __shared__ __align__(16) float smem[STAGE_FLOATS + WS_FLOATS];
    float* wsm = smem + STAGE_FLOATS;
    const int tid = threadIdx.x;
    const size_t tile = blockIdx.x;

    // ---- coalesced float4 staging of the 256-row tile ----
    float4* st4 = (float4*)smem;
    const float4* g0 = (const float4*)(cxr + tile * (size_t)(ROWS * CXR));
    const float4* g1 = (const float4*)(ecg + tile * (size_t)(ROWS * ECG));
    const float4* g2 = (const float4*)(ehr + tile * (size_t)(ROWS * EHR));
    constexpr int N0 = ROWS * CXR / 4;   // 960
    constexpr int N1 = ROWS * ECG / 4;   // 896
    constexpr int N2 = ROWS * EHR / 4;   // 832
#pragma unroll
    for (int it = 0; it < 4; ++it) {
        int idx = tid + it * 256;
        if (idx < N0) st4[idx] = g0[idx];
    }
#pragma unroll
    for (int it = 0; it < 4; ++it) {
        int idx = tid + it * 256;
        if (idx < N1) st4[N0 + idx] = g1[idx];
    }
#pragma unroll
    for (int it = 0; it < 4; ++it) {
        int idx = tid + it * 256;
        if (idx < N2) st4[N0 + N1 + idx] = g2[idx];
    }
    for (int idx = tid; idx < WS_FLOATS; idx += 256) wsm[idx] = ws[idx];
    __syncthreads();

    // ---- per-thread row compute ----
    float ctx[MPITCH];
#pragma unroll
    for (int j = 0; j < CXR; ++j) ctx[j] = smem[S_CXR + tid * CXR + j];
#pragma unroll
    for (int j = 0; j < ECG; ++j) ctx[CXR + j] = smem[S_ECG + tid * ECG + j];
#pragma unroll
    for (int j = 0; j < EHR; ++j) ctx[CXR + ECG + j] = smem[S_EHR + tid * EHR + j];
    ctx[42] = 0.f;
    ctx[43] = 0.f;

    seg_compute<CXR, 0, S_CXR>(ctx, wsm, smem, tid);
    seg_compute<ECG, CXR, S_ECG>(ctx, wsm, smem, tid);
    seg_compute<EHR, CXR + ECG, S_EHR>(ctx, wsm, smem, tid);
    __syncthreads();

    // ---- coalesced float4 stores ----
    float4* o0 = (float4*)(out_cxr + tile * (size_t)(ROWS * CXR));
    float4* o1 = (float4*)(out_ecg + tile * (size_t)(ROWS * ECG));
    float4* o2 = (float4*)(out_ehr + tile * (size_t)(ROWS * EHR));
#pragma unroll
    for (int it = 0; it < 4; ++it) {
        int idx = tid + it * 256;
        if (idx < N0) o0[idx] = st4[idx];
    }
#pragma unroll
    for (int it = 0; it < 4; ++it) {
        int idx = tid + it * 256;
        if (idx < N1) o1[idx] = st4[N0 + idx];
    }
#pragma unroll
    for (int it = 0; it < 4; ++it) {
        int idx = tid + it * 256;
        if (idx < N2) o2[idx] = st4[N0 + N1 + idx];
    }
}

extern "C" void kernel_launch(void* const* d_in, const int* in_sizes, int n_in,
                              void* d_out, int out_size, void* d_ws, size_t ws_size,
                              hipStream_t stream) {
    const float* cxr = (const float*)d_in[0];
    const float* ecg = (const float*)d_in[1];
    const float* ehr = (const float*)d_in[2];
    float* ws = (float*)d_ws;
    float* out = (float*)d_out;

    const size_t Bn = (size_t)in_sizes[0] / CXR;   // 2097152

    auto mk = [&](int base, int E, int R) {
        FuseArgs a;
        a.in_w  = (const float*)d_in[base + 0];
        a.in_b  = (const float*)d_in[base + 1];
        a.out_w = (const float*)d_in[base + 2];
        a.out_b = (const float*)d_in[base + 3];
        a.kv_w  = (const float*)d_in[base + 4];
        a.kv_b  = (const float*)d_in[base + 5];
        a.ln_g  = (const float*)d_in[base + 6];
        a.ln_b  = (const float*)d_in[base + 7];
        a.E = E; a.R = R;
        return a;
    };
    FuseArgs a0 = mk(3, CXR, 0);
    FuseArgs a1 = mk(11, ECG, CXR);
    FuseArgs a2 = mk(19, EHR, CXR + ECG);

    fuse_weights_kernel<<<3, 256, 0, stream>>>(a0, a1, a2, ws);

    const int tiles = (int)(Bn / ROWS);   // 8192
    cmca_main<<<tiles, 256, 0, stream>>>(cxr, ecg, ehr, ws,
                                         out,
                                         out + Bn * CXR,
                                         out + Bn * (CXR + ECG));
}